// Round 1
// 293.586 us; speedup vs baseline: 1.0025x; 1.0025x over previous
//
#include <hip/hip_runtime.h>
#include <hip/hip_bf16.h>

// ---------- types ----------
typedef __bf16 bf16x8 __attribute__((ext_vector_type(8)));
typedef float  f32x4  __attribute__((ext_vector_type(4)));

#define H_DIM 112
#define W_DIM 112
#define CIN 64
#define CMID 192          // 3*64
#define COUT 128
#define NB 16

// ---------------------------------------------------------------
// async 16B global->LDS DMA. LDS dest must be WAVE-UNIFORM; HW adds lane*16.
// ---------------------------------------------------------------
__device__ __forceinline__ void dma16(const void* g, void* l) {
    __builtin_amdgcn_global_load_lds(
        (const __attribute__((address_space(1))) unsigned*)g,
        (__attribute__((address_space(3))) unsigned*)l, 16, 0, 0);
}

// ---------------------------------------------------------------
// Kernel A: repack weights [co][ci][kh][kw] fp32 -> [khw][co][ci] bf16
// ---------------------------------------------------------------
__global__ __launch_bounds__(256) void repack_w_kernel(
    const float* __restrict__ w, __hip_bfloat16* __restrict__ wr)
{
    int idx = blockIdx.x * 256 + threadIdx.x;
    if (idx < 9 * COUT * CMID) {
        int ci  = idx % CMID;
        int t   = idx / CMID;
        int co  = t % COUT;
        int khw = t / COUT;
        wr[idx] = __float2bfloat16(w[(co * CMID + ci) * 9 + khw]);
    }
}

// ---------------------------------------------------------------
// Kernel B: bilinear shift + powers -> y NHWC bf16  [16][112][112][192]
// Stage-then-compute: 32 channels per block (grid 112 x 2 x 16).
// Phase 1: coalesced float4 staging of 64 tap-rows into LDS (zeros if OOB row)
// Phase 2: bilinear + v,v^2,v^3 from LDS -> tile
// Phase 3: coalesced float4 write-out (tile slot = 52 dwords = 13 float4)
// ---------------------------------------------------------------
__global__ __launch_bounds__(256) void shift_pow_kernel(
    const float* __restrict__ x, const float* __restrict__ shifts,
    __hip_bfloat16* __restrict__ y)
{
    __shared__ __align__(16) float xs[64 * 116];               // 29,696 B
    __shared__ __align__(16) __hip_bfloat16 tile[112 * 104];   // 23,296 B
    __shared__ float4 prm[32];

    const int tid = threadIdx.x;
    const int h   = blockIdx.x;
    const int cb  = blockIdx.y * 32;
    const int n   = blockIdx.z;

    if (tid < 32) {
        float sx = shifts[2 * (cb + tid)]     * 4.0f;
        float sy = shifts[2 * (cb + tid) + 1] * 4.0f;
        float fx = floorf(sx), fy = floorf(sy);
        prm[tid] = make_float4(fx, fy, sx - fx, sy - fy);
    }
    __syncthreads();

    // ---- stage 64 tap-rows (32 ch x 2 taps) of 112 floats each ----
    #pragma unroll
    for (int k = 0; k < 7; ++k) {
        int i     = k * 256 + tid;          // 0..1791
        int rowid = i / 28;                 // 0..63
        int part  = i - rowid * 28;         // 0..27 (float4 chunks)
        int c = rowid >> 1, t = rowid & 1;
        int iy = (int)prm[c].y;
        int r  = h + iy + t;
        bool valid = (unsigned)r < (unsigned)H_DIM;
        int rr = min(max(r, 0), H_DIM - 1);
        float4 v = ((const float4*)(
            x + ((size_t)(n * CIN + cb + c) * H_DIM + rr) * W_DIM))[part];
        if (!valid) v = make_float4(0.f, 0.f, 0.f, 0.f);
        *(float4*)&xs[rowid * 116 + part * 4] = v;
    }
    __syncthreads();

    // ---- compute 32 ch x 112 px ----
    #pragma unroll
    for (int k = 0; k < 14; ++k) {
        int i  = k * 256 + tid;             // 0..3583
        int c  = i / 112;
        int px = i - c * 112;
        float4 p = prm[c];
        int ix = (int)p.x;
        float wx = p.z, wy = p.w;
        int q0 = px + ix, q1 = q0 + 1;
        float f0 = ((unsigned)q0 < (unsigned)W_DIM) ? 1.f : 0.f;
        float f1 = ((unsigned)q1 < (unsigned)W_DIM) ? 1.f : 0.f;
        int a0 = min(max(q0, 0), W_DIM - 1);
        int a1 = min(max(q1, 0), W_DIM - 1);
        const float* r0 = &xs[(2 * c) * 116];
        const float* r1 = &xs[(2 * c + 1) * 116];
        float top = (1.f - wx) * f0 * r0[a0] + wx * f1 * r0[a1];
        float bot = (1.f - wx) * f0 * r1[a0] + wx * f1 * r1[a1];
        float v  = (1.f - wy) * top + wy * bot;
        float v2 = v * v, v3 = v2 * v;
        __hip_bfloat16* tp = &tile[px * 104];
        tp[c]      = __float2bfloat16(v);
        tp[c + 32] = __float2bfloat16(v2);
        tp[c + 64] = __float2bfloat16(v3);
    }
    __syncthreads();

    // ---- write out: 112 px x 12 float4 (96 ch bf16) ----
    const float4* tl4 = (const float4*)tile;   // 13 f4 per px slot
    float4* yo4 = (float4*)(y + ((size_t)(n * H_DIM + h) * W_DIM) * CMID); // 24 f4/px
    const int cbd4 = cb >> 3;                  // 0 or 4 (float4 units)
    #pragma unroll
    for (int k = 0; k < 6; ++k) {
        int i = k * 256 + tid;                 // 0..1535 (1344 valid)
        if (i < 1344) {
            int px  = i / 12;
            int cp4 = i - px * 12;             // 0..11
            int chunk = cp4 >> 2, e4 = cp4 & 3;
            yo4[px * 24 + chunk * 8 + cbd4 + e4] = tl4[px * 13 + cp4];
        }
    }
}

// ---------------------------------------------------------------
// Kernel C: implicit-GEMM 3x3 conv, bf16 MFMA 16x16x32.
// m97-style async pipeline: steps = (kh, half of 96 ch); double-buffered LDS
// staged via global_load_lds (width 16); ONE barrier per step, DMA for step
// s+1 issued before compute(s) so it drains (vmcnt) only at the step barrier.
// Block = 128 co x 112 px (one output row), wave = 32 co x 112 px (mt2, nt7).
// LDS slot stride 208 B (104 elems): 192 B data + 16 B pad (pad lane masked).
//
// Inner loop is REGISTER-BATCHED: per (c3,kw) all 7 B-fragments are loaded
// into VGPRs (one per-lane base + compile-time immediate offsets) before the
// 14-MFMA cluster, so the scheduler can issue 7 independent ds_read_b128
// back-to-back instead of serializing read -> lgkmcnt(0) -> 2 MFMA (which
// exposed ~120cy LDS latency per 39cy of MFMA: the measured 23% MfmaUtil).
// ---------------------------------------------------------------
#define YSTR_E 104                  // elements per px slot (208 B)
#define BUF_E  12288                // 24,576 B per buffer (covers DMA overrun)

__global__ __launch_bounds__(256, 3) void conv_kernel(
    const __bf16* __restrict__ y,    // [16][112][112][192]
    const __bf16* __restrict__ wr,   // [9][128][192]
    const float* __restrict__ bias,
    float* __restrict__ out)         // [16][128][112][112]
{
    __shared__ __align__(16) __bf16 ybuf[2][BUF_E];   // 49,152 B

    const int tid  = threadIdx.x;
    const int lane = tid & 63;
    const int wid  = tid >> 6;
    const int m    = lane & 15;
    const int quad = lane >> 4;

    const int h = blockIdx.x;
    const int n = blockIdx.y;

    // zero halo slots (slot 0 = px -1, slot 113 = px 112) of both buffers
    if (tid < 208) {
        int b    = tid >= 104;
        int r    = tid - b * 104;
        int slot = (r >= 52) ? 113 : 0;
        int dw   = (r >= 52) ? r - 52 : r;
        ((unsigned*)&ybuf[b][0])[slot * 52 + dw] = 0u;
    }

    // per-lane DMA source-offset table: chunk t = 4*j + wid, LDS byte
    // o = 208 + 1024*t + 16*lane -> slot = o/208, rem = o%208.
    // valid data lane iff rem<192 and slot in [1,112]; global byte offset
    // within (row,half) = (slot-1)*384 + rem.
    int dj[6];
    #pragma unroll
    for (int j = 0; j < 6; ++j) {
        int t = 4 * j + wid;
        int o = 208 + 1024 * t + 16 * lane;
        int slot = o / 208;
        int rem  = o - slot * 208;
        dj[j] = (t < 23 && rem < 192 && slot <= 112)
                    ? ((slot - 1) * 384 + rem) : -1;
    }

    f32x4 acc[2][7];
    #pragma unroll
    for (int mt = 0; mt < 2; ++mt)
        #pragma unroll
        for (int nt = 0; nt < 7; ++nt)
            #pragma unroll
            for (int r = 0; r < 4; ++r) acc[mt][nt][r] = 0.0f;

    const char* ybase = (const char*)y + (size_t)n * (H_DIM * W_DIM * CMID * 2);

    // step s: kh = s>>1 (row h+kh-1), half = s&1 (channels half*96 ..)
    const int f = (h == 0)         ? 2 : 0;
    const int l = (h == H_DIM - 1) ? 3 : 5;

    // ---- stage step f into buffer 0 ----
    {
        int row = h + (f >> 1) - 1, half = f & 1;
        const char* src = ybase + (size_t)row * (W_DIM * CMID * 2) + half * 192;
        char* lb = (char*)&ybuf[0][0];
        #pragma unroll
        for (int j = 0; j < 6; ++j) {
            int t = 4 * j + wid;
            if (dj[j] >= 0) dma16(src + dj[j], lb + 208 + 1024 * t);
        }
    }
    __syncthreads();   // drains first stage

    int buf = 0;
    for (int s = f; s <= l; ++s) {
        // issue async stage of step s+1 into the other buffer
        if (s < l) {
            int row = h + ((s + 1) >> 1) - 1, half = (s + 1) & 1;
            const char* src = ybase + (size_t)row * (W_DIM * CMID * 2) + half * 192;
            char* lb = (char*)&ybuf[buf ^ 1][0];
            #pragma unroll
            for (int j = 0; j < 6; ++j) {
                int t = 4 * j + wid;
                if (dj[j] >= 0) dma16(src + dj[j], lb + 208 + 1024 * t);
            }
        }

        // compute step s from ybuf[buf]
        const int kh = s >> 1, half = s & 1;
        // single per-lane LDS base; all 63 reads use compile-time offsets
        const __bf16* lbase = &ybuf[buf][m * YSTR_E + quad * 8];
        #pragma unroll
        for (int c3 = 0; c3 < 3; ++c3) {
            const int ci = half * 96 + c3 * 32 + quad * 8; // global channel
            bf16x8 af[3][2];
            #pragma unroll
            for (int kw = 0; kw < 3; ++kw)
                #pragma unroll
                for (int mt = 0; mt < 2; ++mt)
                    af[kw][mt] = *(const bf16x8*)(
                        wr + (size_t)((kh * 3 + kw) * COUT + wid * 32 + mt * 16 + m) * CMID + ci);
            #pragma unroll
            for (int kw = 0; kw < 3; ++kw) {
                bf16x8 bfr[7];
                #pragma unroll
                for (int nt = 0; nt < 7; ++nt)
                    bfr[nt] = *(const bf16x8*)(lbase + (nt * 16 + kw) * YSTR_E + c3 * 32);
                #pragma unroll
                for (int nt = 0; nt < 7; ++nt) {
                    acc[0][nt] = __builtin_amdgcn_mfma_f32_16x16x32_bf16(
                        af[kw][0], bfr[nt], acc[0][nt], 0, 0, 0);
                    acc[1][nt] = __builtin_amdgcn_mfma_f32_16x16x32_bf16(
                        af[kw][1], bfr[nt], acc[1][nt], 0, 0, 0);
                }
            }
        }
        __syncthreads();   // drains stage(s+1) DMA + protects buffer reuse
        buf ^= 1;
    }

    // epilogue: D col = px (lane&15), row = quad*4+r -> co
    #pragma unroll
    for (int mt = 0; mt < 2; ++mt) {
        const int co0 = wid * 32 + mt * 16 + quad * 4;
        float bv[4];
        #pragma unroll
        for (int rr = 0; rr < 4; ++rr) bv[rr] = bias[co0 + rr];
        #pragma unroll
        for (int nt = 0; nt < 7; ++nt) {
            int j = nt * 16 + m;
            #pragma unroll
            for (int rr = 0; rr < 4; ++rr) {
                out[(((size_t)n * COUT + co0 + rr) * H_DIM + h) * W_DIM + j] =
                    acc[mt][nt][rr] + bv[rr];
            }
        }
    }
}

// ---------------------------------------------------------------
extern "C" void kernel_launch(void* const* d_in, const int* in_sizes, int n_in,
                              void* d_out, int out_size, void* d_ws, size_t ws_size,
                              hipStream_t stream) {
    const float* x      = (const float*)d_in[0];
    const float* w      = (const float*)d_in[1];
    const float* bias   = (const float*)d_in[2];
    const float* shifts = (const float*)d_in[3];
    float* out = (float*)d_out;

    __hip_bfloat16* y  = (__hip_bfloat16*)d_ws;                       // 77,070,336 B
    __hip_bfloat16* wr = (__hip_bfloat16*)((char*)d_ws + 77070336);   //    442,368 B

    repack_w_kernel<<<dim3((9 * COUT * CMID + 255) / 256), 256, 0, stream>>>(w, wr);
    shift_pow_kernel<<<dim3(H_DIM, 2, NB), 256, 0, stream>>>(x, shifts, y);
    conv_kernel<<<dim3(H_DIM, NB), 256, 0, stream>>>(
        (const __bf16*)y, (const __bf16*)wr, bias, out);
}

// Round 3
// 287.525 us; speedup vs baseline: 1.0236x; 1.0211x over previous
//
#include <hip/hip_runtime.h>
#include <hip/hip_bf16.h>

// ---------- types ----------
typedef __bf16 bf16x8 __attribute__((ext_vector_type(8)));
typedef float  f32x4  __attribute__((ext_vector_type(4)));

#define H_DIM 112
#define W_DIM 112
#define CIN 64
#define CMID 192          // 3*64
#define COUT 128
#define NB 16

// ---------------------------------------------------------------
// async 16B global->LDS DMA. LDS dest must be WAVE-UNIFORM; HW adds lane*16.
// ---------------------------------------------------------------
__device__ __forceinline__ void dma16(const void* g, void* l) {
    __builtin_amdgcn_global_load_lds(
        (const __attribute__((address_space(1))) unsigned*)g,
        (__attribute__((address_space(3))) unsigned*)l, 16, 0, 0);
}

// ---------------------------------------------------------------
// Kernel A: repack weights [co][ci][kh][kw] fp32 -> [khw][co][ci] bf16
// ---------------------------------------------------------------
__global__ __launch_bounds__(256) void repack_w_kernel(
    const float* __restrict__ w, __hip_bfloat16* __restrict__ wr)
{
    int idx = blockIdx.x * 256 + threadIdx.x;
    if (idx < 9 * COUT * CMID) {
        int ci  = idx % CMID;
        int t   = idx / CMID;
        int co  = t % COUT;
        int khw = t / COUT;
        wr[idx] = __float2bfloat16(w[(co * CMID + ci) * 9 + khw]);
    }
}

// ---------------------------------------------------------------
// Kernel B: bilinear shift + powers -> y NHWC bf16  [16][112][112][192]
// ---------------------------------------------------------------
__global__ __launch_bounds__(256) void shift_pow_kernel(
    const float* __restrict__ x, const float* __restrict__ shifts,
    __hip_bfloat16* __restrict__ y)
{
    __shared__ __align__(16) float xs[64 * 116];               // 29,696 B
    __shared__ __align__(16) __hip_bfloat16 tile[112 * 104];   // 23,296 B
    __shared__ float4 prm[32];

    const int tid = threadIdx.x;
    const int h   = blockIdx.x;
    const int cb  = blockIdx.y * 32;
    const int n   = blockIdx.z;

    if (tid < 32) {
        float sx = shifts[2 * (cb + tid)]     * 4.0f;
        float sy = shifts[2 * (cb + tid) + 1] * 4.0f;
        float fx = floorf(sx), fy = floorf(sy);
        prm[tid] = make_float4(fx, fy, sx - fx, sy - fy);
    }
    __syncthreads();

    // ---- stage 64 tap-rows (32 ch x 2 taps) of 112 floats each ----
    #pragma unroll
    for (int k = 0; k < 7; ++k) {
        int i     = k * 256 + tid;          // 0..1791
        int rowid = i / 28;                 // 0..63
        int part  = i - rowid * 28;         // 0..27 (float4 chunks)
        int c = rowid >> 1, t = rowid & 1;
        int iy = (int)prm[c].y;
        int r  = h + iy + t;
        bool valid = (unsigned)r < (unsigned)H_DIM;
        int rr = min(max(r, 0), H_DIM - 1);
        float4 v = ((const float4*)(
            x + ((size_t)(n * CIN + cb + c) * H_DIM + rr) * W_DIM))[part];
        if (!valid) v = make_float4(0.f, 0.f, 0.f, 0.f);
        *(float4*)&xs[rowid * 116 + part * 4] = v;
    }
    __syncthreads();

    // ---- compute 32 ch x 112 px ----
    #pragma unroll
    for (int k = 0; k < 14; ++k) {
        int i  = k * 256 + tid;             // 0..3583
        int c  = i / 112;
        int px = i - c * 112;
        float4 p = prm[c];
        int ix = (int)p.x;
        float wx = p.z, wy = p.w;
        int q0 = px + ix, q1 = q0 + 1;
        float f0 = ((unsigned)q0 < (unsigned)W_DIM) ? 1.f : 0.f;
        float f1 = ((unsigned)q1 < (unsigned)W_DIM) ? 1.f : 0.f;
        int a0 = min(max(q0, 0), W_DIM - 1);
        int a1 = min(max(q1, 0), W_DIM - 1);
        const float* r0 = &xs[(2 * c) * 116];
        const float* r1 = &xs[(2 * c + 1) * 116];
        float top = (1.f - wx) * f0 * r0[a0] + wx * f1 * r0[a1];
        float bot = (1.f - wx) * f0 * r1[a0] + wx * f1 * r1[a1];
        float v  = (1.f - wy) * top + wy * bot;
        float v2 = v * v, v3 = v2 * v;
        __hip_bfloat16* tp = &tile[px * 104];
        tp[c]      = __float2bfloat16(v);
        tp[c + 32] = __float2bfloat16(v2);
        tp[c + 64] = __float2bfloat16(v3);
    }
    __syncthreads();

    // ---- write out: 112 px x 12 float4 (96 ch bf16) ----
    const float4* tl4 = (const float4*)tile;   // 13 f4 per px slot
    float4* yo4 = (float4*)(y + ((size_t)(n * H_DIM + h) * W_DIM) * CMID); // 24 f4/px
    const int cbd4 = cb >> 3;                  // 0 or 4 (float4 units)
    #pragma unroll
    for (int k = 0; k < 6; ++k) {
        int i = k * 256 + tid;                 // 0..1535 (1344 valid)
        if (i < 1344) {
            int px  = i / 12;
            int cp4 = i - px * 12;             // 0..11
            int chunk = cp4 >> 2, e4 = cp4 & 3;
            yo4[px * 24 + chunk * 8 + cbd4 + e4] = tl4[px * 13 + cp4];
        }
    }
}

// ---------------------------------------------------------------
// Kernel C: implicit-GEMM 3x3 conv, bf16 MFMA 16x16x32.
// Double-buffered global_load_lds staging (one barrier per step) + a
// REGISTER-double-buffered inner loop whose interleave is PINNED with
// sched_group_barrier: per (c3,kw) group, the 7 B-fragments of the NEXT
// group are ds_read while the current group's 14 MFMAs run, emitted as
// [1xDS_READ, 2xMFMA] x7. Round-1 showed the scheduler sinks source-level
// batched loads back to their uses (VGPR stayed 68); SGB forces the issue
// distance so each ds_read lands ~270cy before use (> ~120cy LDS latency).
// All 18 weight fragments for a step are hoisted (global latency off the
// critical path). XCD-chunked block swizzle: adjacent h (sharing 2/3 of y
// rows) land on the same XCD L2.
// ROUND-2 FIX: hoisted weight address was missing "+ quad*8" (per-lane K
// slice) -> absmax 20. Restored; everything else identical.
// ---------------------------------------------------------------
#define YSTR_E 104                  // elements per px slot (208 B)
#define BUF_E  12288                // 24,576 B per buffer (covers DMA overrun)

#define CONV_GROUP(G, CUR, NXT) do {                                          \
    const int c3_ = (G) / 3, kw_ = (G) % 3;                                   \
    if ((G) < 8) {                                                            \
        const int c3n_ = ((G) + 1) / 3, kwn_ = ((G) + 1) % 3;                 \
        _Pragma("unroll")                                                     \
        for (int nt = 0; nt < 7; ++nt)                                        \
            NXT[nt] = *(const bf16x8*)(lbase +                                \
                (nt * 16 + kwn_) * YSTR_E + c3n_ * 32);                       \
    }                                                                         \
    _Pragma("unroll")                                                         \
    for (int nt = 0; nt < 7; ++nt) {                                          \
        acc[0][nt] = __builtin_amdgcn_mfma_f32_16x16x32_bf16(                 \
            af[c3_][kw_][0], CUR[nt], acc[0][nt], 0, 0, 0);                   \
        acc[1][nt] = __builtin_amdgcn_mfma_f32_16x16x32_bf16(                 \
            af[c3_][kw_][1], CUR[nt], acc[1][nt], 0, 0, 0);                   \
    }                                                                         \
    if ((G) < 8) {                                                            \
        _Pragma("unroll")                                                     \
        for (int k_ = 0; k_ < 7; ++k_) {                                      \
            __builtin_amdgcn_sched_group_barrier(0x100, 1, 0); /* DS_READ */  \
            __builtin_amdgcn_sched_group_barrier(0x008, 2, 0); /* MFMA   */   \
        }                                                                     \
    } else {                                                                  \
        __builtin_amdgcn_sched_group_barrier(0x008, 14, 0);                   \
    }                                                                         \
} while (0)

__global__ __launch_bounds__(256, 2) void conv_kernel(
    const __bf16* __restrict__ y,    // [16][112][112][192]
    const __bf16* __restrict__ wr,   // [9][128][192]
    const float* __restrict__ bias,
    float* __restrict__ out)         // [16][128][112][112]
{
    __shared__ __align__(16) __bf16 ybuf[2][BUF_E];   // 49,152 B

    const int tid  = threadIdx.x;
    const int lane = tid & 63;
    const int wid  = tid >> 6;
    const int m    = lane & 15;
    const int quad = lane >> 4;

    // XCD-chunked swizzle: grid 1792 = 8 XCDs x 224; consecutive ids within
    // a chunk are consecutive h (same n) -> y-row reuse stays in one L2.
    const int bid = blockIdx.x;
    const int id  = (bid & 7) * 224 + (bid >> 3);
    const int n   = id / H_DIM;
    const int h   = id - n * H_DIM;

    // zero halo slots (slot 0 = px -1, slot 113 = px 112) of both buffers
    if (tid < 208) {
        int b    = tid >= 104;
        int r    = tid - b * 104;
        int slot = (r >= 52) ? 113 : 0;
        int dw   = (r >= 52) ? r - 52 : r;
        ((unsigned*)&ybuf[b][0])[slot * 52 + dw] = 0u;
    }

    // per-lane DMA source-offset table: chunk t = 4*j + wid, LDS byte
    // o = 208 + 1024*t + 16*lane -> slot = o/208, rem = o%208.
    int dj[6];
    #pragma unroll
    for (int j = 0; j < 6; ++j) {
        int t = 4 * j + wid;
        int o = 208 + 1024 * t + 16 * lane;
        int slot = o / 208;
        int rem  = o - slot * 208;
        dj[j] = (t < 23 && rem < 192 && slot <= 112)
                    ? ((slot - 1) * 384 + rem) : -1;
    }

    f32x4 acc[2][7];
    #pragma unroll
    for (int mt = 0; mt < 2; ++mt)
        #pragma unroll
        for (int nt = 0; nt < 7; ++nt)
            #pragma unroll
            for (int r = 0; r < 4; ++r) acc[mt][nt][r] = 0.0f;

    const char* ybase = (const char*)y + (size_t)n * (H_DIM * W_DIM * CMID * 2);

    // step s: kh = s>>1 (row h+kh-1), half = s&1 (channels half*96 ..)
    const int f = (h == 0)         ? 2 : 0;
    const int l = (h == H_DIM - 1) ? 3 : 5;

    // ---- stage step f into buffer 0 ----
    {
        int row = h + (f >> 1) - 1, half = f & 1;
        const char* src = ybase + (size_t)row * (W_DIM * CMID * 2) + half * 192;
        char* lb = (char*)&ybuf[0][0];
        #pragma unroll
        for (int j = 0; j < 6; ++j) {
            int t = 4 * j + wid;
            if (dj[j] >= 0) dma16(src + dj[j], lb + 208 + 1024 * t);
        }
    }
    __syncthreads();   // drains first stage

    int buf = 0;
    for (int s = f; s <= l; ++s) {
        // issue async stage of step s+1 into the other buffer
        if (s < l) {
            int row = h + ((s + 1) >> 1) - 1, half = (s + 1) & 1;
            const char* src = ybase + (size_t)row * (W_DIM * CMID * 2) + half * 192;
            char* lb = (char*)&ybuf[buf ^ 1][0];
            #pragma unroll
            for (int j = 0; j < 6; ++j) {
                int t = 4 * j + wid;
                if (dj[j] >= 0) dma16(src + dj[j], lb + 208 + 1024 * t);
            }
        }

        // compute step s from ybuf[buf]
        const int kh = s >> 1, half = s & 1;
        const __bf16* lbase = &ybuf[buf][m * YSTR_E + quad * 8];

        // hoist ALL 18 weight fragments for this step (VMEM latency off
        // the inner loop); per-lane K slice = half*96 + c3*32 + quad*8
        bf16x8 af[3][3][2];
        #pragma unroll
        for (int c3 = 0; c3 < 3; ++c3)
            #pragma unroll
            for (int kw = 0; kw < 3; ++kw)
                #pragma unroll
                for (int mt = 0; mt < 2; ++mt)
                    af[c3][kw][mt] = *(const bf16x8*)(
                        wr + (size_t)((kh * 3 + kw) * COUT + wid * 32 + mt * 16 + m) * CMID
                           + half * 96 + c3 * 32 + quad * 8);

        // prologue: group 0 fragments into bA
        bf16x8 bA[7], bB[7];
        #pragma unroll
        for (int nt = 0; nt < 7; ++nt)
            bA[nt] = *(const bf16x8*)(lbase + (nt * 16 + 0) * YSTR_E + 0 * 32);
        __builtin_amdgcn_sched_group_barrier(0x100, 7, 0);   // 7x DS_READ

        CONV_GROUP(0, bA, bB);
        CONV_GROUP(1, bB, bA);
        CONV_GROUP(2, bA, bB);
        CONV_GROUP(3, bB, bA);
        CONV_GROUP(4, bA, bB);
        CONV_GROUP(5, bB, bA);
        CONV_GROUP(6, bA, bB);
        CONV_GROUP(7, bB, bA);
        CONV_GROUP(8, bA, bB);

        __syncthreads();   // drains stage(s+1) DMA + protects buffer reuse
        buf ^= 1;
    }

    // epilogue: D col = px (lane&15), row = quad*4+r -> co
    #pragma unroll
    for (int mt = 0; mt < 2; ++mt) {
        const int co0 = wid * 32 + mt * 16 + quad * 4;
        float bv[4];
        #pragma unroll
        for (int rr = 0; rr < 4; ++rr) bv[rr] = bias[co0 + rr];
        #pragma unroll
        for (int nt = 0; nt < 7; ++nt) {
            int j = nt * 16 + m;
            #pragma unroll
            for (int rr = 0; rr < 4; ++rr) {
                out[(((size_t)n * COUT + co0 + rr) * H_DIM + h) * W_DIM + j] =
                    acc[mt][nt][rr] + bv[rr];
            }
        }
    }
}

// ---------------------------------------------------------------
extern "C" void kernel_launch(void* const* d_in, const int* in_sizes, int n_in,
                              void* d_out, int out_size, void* d_ws, size_t ws_size,
                              hipStream_t stream) {
    const float* x      = (const float*)d_in[0];
    const float* w      = (const float*)d_in[1];
    const float* bias   = (const float*)d_in[2];
    const float* shifts = (const float*)d_in[3];
    float* out = (float*)d_out;

    __hip_bfloat16* y  = (__hip_bfloat16*)d_ws;                       // 77,070,336 B
    __hip_bfloat16* wr = (__hip_bfloat16*)((char*)d_ws + 77070336);   //    442,368 B

    repack_w_kernel<<<dim3((9 * COUT * CMID + 255) / 256), 256, 0, stream>>>(w, wr);
    shift_pow_kernel<<<dim3(H_DIM, 2, NB), 256, 0, stream>>>(x, shifts, y);
    conv_kernel<<<dim3(H_DIM * NB), 256, 0, stream>>>(
        (const __bf16*)y, (const __bf16*)wr, bias, out);
}

// Round 4
// 273.975 us; speedup vs baseline: 1.0742x; 1.0495x over previous
//
#include <hip/hip_runtime.h>
#include <hip/hip_bf16.h>

// ---------- types ----------
typedef __bf16 bf16x8 __attribute__((ext_vector_type(8)));
typedef float  f32x4  __attribute__((ext_vector_type(4)));

#define H_DIM 112
#define W_DIM 112
#define CIN 64
#define CMID 192          // 3*64
#define COUT 128
#define NB 16

// ---------------------------------------------------------------
// async 16B global->LDS DMA. LDS dest must be WAVE-UNIFORM; HW adds lane*16.
// ---------------------------------------------------------------
__device__ __forceinline__ void dma16(const void* g, void* l) {
    __builtin_amdgcn_global_load_lds(
        (const __attribute__((address_space(1))) unsigned*)g,
        (__attribute__((address_space(3))) unsigned*)l, 16, 0, 0);
}

// ---------------------------------------------------------------
// Kernel A: repack weights [co][ci][kh][kw] fp32 -> [khw][co][ci] bf16
// ---------------------------------------------------------------
__global__ __launch_bounds__(256) void repack_w_kernel(
    const float* __restrict__ w, __hip_bfloat16* __restrict__ wr)
{
    int idx = blockIdx.x * 256 + threadIdx.x;
    if (idx < 9 * COUT * CMID) {
        int ci  = idx % CMID;
        int t   = idx / CMID;
        int co  = t % COUT;
        int khw = t / COUT;
        wr[idx] = __float2bfloat16(w[(co * CMID + ci) * 9 + khw]);
    }
}

// ---------------------------------------------------------------
// Kernel B: bilinear shift + powers -> y NHWC bf16  [16][112][112][192]
// ---------------------------------------------------------------
__global__ __launch_bounds__(256) void shift_pow_kernel(
    const float* __restrict__ x, const float* __restrict__ shifts,
    __hip_bfloat16* __restrict__ y)
{
    __shared__ __align__(16) float xs[64 * 116];               // 29,696 B
    __shared__ __align__(16) __hip_bfloat16 tile[112 * 104];   // 23,296 B
    __shared__ float4 prm[32];

    const int tid = threadIdx.x;
    const int h   = blockIdx.x;
    const int cb  = blockIdx.y * 32;
    const int n   = blockIdx.z;

    if (tid < 32) {
        float sx = shifts[2 * (cb + tid)]     * 4.0f;
        float sy = shifts[2 * (cb + tid) + 1] * 4.0f;
        float fx = floorf(sx), fy = floorf(sy);
        prm[tid] = make_float4(fx, fy, sx - fx, sy - fy);
    }
    __syncthreads();

    // ---- stage 64 tap-rows (32 ch x 2 taps) of 112 floats each ----
    #pragma unroll
    for (int k = 0; k < 7; ++k) {
        int i     = k * 256 + tid;          // 0..1791
        int rowid = i / 28;                 // 0..63
        int part  = i - rowid * 28;         // 0..27 (float4 chunks)
        int c = rowid >> 1, t = rowid & 1;
        int iy = (int)prm[c].y;
        int r  = h + iy + t;
        bool valid = (unsigned)r < (unsigned)H_DIM;
        int rr = min(max(r, 0), H_DIM - 1);
        float4 v = ((const float4*)(
            x + ((size_t)(n * CIN + cb + c) * H_DIM + rr) * W_DIM))[part];
        if (!valid) v = make_float4(0.f, 0.f, 0.f, 0.f);
        *(float4*)&xs[rowid * 116 + part * 4] = v;
    }
    __syncthreads();

    // ---- compute 32 ch x 112 px ----
    #pragma unroll
    for (int k = 0; k < 14; ++k) {
        int i  = k * 256 + tid;             // 0..3583
        int c  = i / 112;
        int px = i - c * 112;
        float4 p = prm[c];
        int ix = (int)p.x;
        float wx = p.z, wy = p.w;
        int q0 = px + ix, q1 = q0 + 1;
        float f0 = ((unsigned)q0 < (unsigned)W_DIM) ? 1.f : 0.f;
        float f1 = ((unsigned)q1 < (unsigned)W_DIM) ? 1.f : 0.f;
        int a0 = min(max(q0, 0), W_DIM - 1);
        int a1 = min(max(q1, 0), W_DIM - 1);
        const float* r0 = &xs[(2 * c) * 116];
        const float* r1 = &xs[(2 * c + 1) * 116];
        float top = (1.f - wx) * f0 * r0[a0] + wx * f1 * r0[a1];
        float bot = (1.f - wx) * f0 * r1[a0] + wx * f1 * r1[a1];
        float v  = (1.f - wy) * top + wy * bot;
        float v2 = v * v, v3 = v2 * v;
        __hip_bfloat16* tp = &tile[px * 104];
        tp[c]      = __float2bfloat16(v);
        tp[c + 32] = __float2bfloat16(v2);
        tp[c + 64] = __float2bfloat16(v3);
    }
    __syncthreads();

    // ---- write out: 112 px x 12 float4 (96 ch bf16) ----
    const float4* tl4 = (const float4*)tile;   // 13 f4 per px slot
    float4* yo4 = (float4*)(y + ((size_t)(n * H_DIM + h) * W_DIM) * CMID); // 24 f4/px
    const int cbd4 = cb >> 3;                  // 0 or 4 (float4 units)
    #pragma unroll
    for (int k = 0; k < 6; ++k) {
        int i = k * 256 + tid;                 // 0..1535 (1344 valid)
        if (i < 1344) {
            int px  = i / 12;
            int cp4 = i - px * 12;             // 0..11
            int chunk = cp4 >> 2, e4 = cp4 & 3;
            yo4[px * 24 + chunk * 8 + cbd4 + e4] = tl4[px * 13 + cp4];
        }
    }
}

// ---------------------------------------------------------------
// Kernel C: implicit-GEMM 3x3 conv, bf16 MFMA 16x16x32.
// Double-buffered global_load_lds staging (one barrier per step) +
// register-double-buffered inner loop pinned with sched_group_barrier
// ([1xDS_READ, 2xMFMA] x7 per group).
//
// ROUND-4 CHANGE (vmcnt ordering): the af weight loads are issued BEFORE
// the step-(s+1) DMA, with sched_barrier(0) pinning the order. vmcnt
// completion is in-order, so previously the first MFMA (needing af, which
// was YOUNGER than all 23 DMAs) forced a full DMA drain at the TOP of
// every step -- the prefetch was serialized into the compute. With af
// oldest, the MFMA wait is vmcnt(23): af done, DMAs still in flight until
// the end-of-step barrier where they belong.
// ---------------------------------------------------------------
#define YSTR_E 104                  // elements per px slot (208 B)
#define BUF_E  12288                // 24,576 B per buffer (covers DMA overrun)

#define CONV_GROUP(G, CUR, NXT) do {                                          \
    const int c3_ = (G) / 3, kw_ = (G) % 3;                                   \
    if ((G) < 8) {                                                            \
        const int c3n_ = ((G) + 1) / 3, kwn_ = ((G) + 1) % 3;                 \
        _Pragma("unroll")                                                     \
        for (int nt = 0; nt < 7; ++nt)                                        \
            NXT[nt] = *(const bf16x8*)(lbase +                                \
                (nt * 16 + kwn_) * YSTR_E + c3n_ * 32);                       \
    }                                                                         \
    _Pragma("unroll")                                                         \
    for (int nt = 0; nt < 7; ++nt) {                                          \
        acc[0][nt] = __builtin_amdgcn_mfma_f32_16x16x32_bf16(                 \
            af[c3_][kw_][0], CUR[nt], acc[0][nt], 0, 0, 0);                   \
        acc[1][nt] = __builtin_amdgcn_mfma_f32_16x16x32_bf16(                 \
            af[c3_][kw_][1], CUR[nt], acc[1][nt], 0, 0, 0);                   \
    }                                                                         \
    if ((G) < 8) {                                                            \
        _Pragma("unroll")                                                     \
        for (int k_ = 0; k_ < 7; ++k_) {                                      \
            __builtin_amdgcn_sched_group_barrier(0x100, 1, 0); /* DS_READ */  \
            __builtin_amdgcn_sched_group_barrier(0x008, 2, 0); /* MFMA   */   \
        }                                                                     \
    } else {                                                                  \
        __builtin_amdgcn_sched_group_barrier(0x008, 14, 0);                   \
    }                                                                         \
} while (0)

__global__ __launch_bounds__(256, 2) void conv_kernel(
    const __bf16* __restrict__ y,    // [16][112][112][192]
    const __bf16* __restrict__ wr,   // [9][128][192]
    const float* __restrict__ bias,
    float* __restrict__ out)         // [16][128][112][112]
{
    __shared__ __align__(16) __bf16 ybuf[2][BUF_E];   // 49,152 B

    const int tid  = threadIdx.x;
    const int lane = tid & 63;
    const int wid  = tid >> 6;
    const int m    = lane & 15;
    const int quad = lane >> 4;

    // XCD-chunked swizzle: grid 1792 = 8 XCDs x 224; consecutive ids within
    // a chunk are consecutive h (same n) -> y-row reuse stays in one L2.
    const int bid = blockIdx.x;
    const int id  = (bid & 7) * 224 + (bid >> 3);
    const int n   = id / H_DIM;
    const int h   = id - n * H_DIM;

    // zero halo slots (slot 0 = px -1, slot 113 = px 112) of both buffers
    if (tid < 208) {
        int b    = tid >= 104;
        int r    = tid - b * 104;
        int slot = (r >= 52) ? 113 : 0;
        int dw   = (r >= 52) ? r - 52 : r;
        ((unsigned*)&ybuf[b][0])[slot * 52 + dw] = 0u;
    }

    // per-lane DMA source-offset table: chunk t = 4*j + wid, LDS byte
    // o = 208 + 1024*t + 16*lane -> slot = o/208, rem = o%208.
    int dj[6];
    #pragma unroll
    for (int j = 0; j < 6; ++j) {
        int t = 4 * j + wid;
        int o = 208 + 1024 * t + 16 * lane;
        int slot = o / 208;
        int rem  = o - slot * 208;
        dj[j] = (t < 23 && rem < 192 && slot <= 112)
                    ? ((slot - 1) * 384 + rem) : -1;
    }

    f32x4 acc[2][7];
    #pragma unroll
    for (int mt = 0; mt < 2; ++mt)
        #pragma unroll
        for (int nt = 0; nt < 7; ++nt)
            #pragma unroll
            for (int r = 0; r < 4; ++r) acc[mt][nt][r] = 0.0f;

    const char* ybase = (const char*)y + (size_t)n * (H_DIM * W_DIM * CMID * 2);

    // step s: kh = s>>1 (row h+kh-1), half = s&1 (channels half*96 ..)
    const int f = (h == 0)         ? 2 : 0;
    const int l = (h == H_DIM - 1) ? 3 : 5;

    // ---- stage step f into buffer 0 ----
    {
        int row = h + (f >> 1) - 1, half = f & 1;
        const char* src = ybase + (size_t)row * (W_DIM * CMID * 2) + half * 192;
        char* lb = (char*)&ybuf[0][0];
        #pragma unroll
        for (int j = 0; j < 6; ++j) {
            int t = 4 * j + wid;
            if (dj[j] >= 0) dma16(src + dj[j], lb + 208 + 1024 * t);
        }
    }
    __syncthreads();   // drains first stage

    int buf = 0;
    for (int s = f; s <= l; ++s) {
        const int kh = s >> 1, half = s & 1;

        // ---- (1) af weight loads FIRST (oldest vmcnt entries) ----
        // per-lane K slice = half*96 + c3*32 + quad*8
        bf16x8 af[3][3][2];
        #pragma unroll
        for (int c3 = 0; c3 < 3; ++c3)
            #pragma unroll
            for (int kw = 0; kw < 3; ++kw)
                #pragma unroll
                for (int mt = 0; mt < 2; ++mt)
                    af[c3][kw][mt] = *(const bf16x8*)(
                        wr + (size_t)((kh * 3 + kw) * COUT + wid * 32 + mt * 16 + m) * CMID
                           + half * 96 + c3 * 32 + quad * 8);

        // pin: DMAs below must NOT hoist above the af loads (no-alias would
        // otherwise allow the scheduler to undo the vmcnt ordering)
        __builtin_amdgcn_sched_barrier(0);

        // ---- (2) issue async stage of step s+1 into the other buffer ----
        if (s < l) {
            int row = h + ((s + 1) >> 1) - 1, halfn = (s + 1) & 1;
            const char* src = ybase + (size_t)row * (W_DIM * CMID * 2) + halfn * 192;
            char* lb = (char*)&ybuf[buf ^ 1][0];
            #pragma unroll
            for (int j = 0; j < 6; ++j) {
                int t = 4 * j + wid;
                if (dj[j] >= 0) dma16(src + dj[j], lb + 208 + 1024 * t);
            }
        }

        // ---- (3) compute step s from ybuf[buf] ----
        const __bf16* lbase = &ybuf[buf][m * YSTR_E + quad * 8];

        // prologue: group 0 fragments into bA
        bf16x8 bA[7], bB[7];
        #pragma unroll
        for (int nt = 0; nt < 7; ++nt)
            bA[nt] = *(const bf16x8*)(lbase + (nt * 16 + 0) * YSTR_E + 0 * 32);
        __builtin_amdgcn_sched_group_barrier(0x100, 7, 0);   // 7x DS_READ

        CONV_GROUP(0, bA, bB);
        CONV_GROUP(1, bB, bA);
        CONV_GROUP(2, bA, bB);
        CONV_GROUP(3, bB, bA);
        CONV_GROUP(4, bA, bB);
        CONV_GROUP(5, bB, bA);
        CONV_GROUP(6, bA, bB);
        CONV_GROUP(7, bB, bA);
        CONV_GROUP(8, bA, bB);

        __syncthreads();   // drains stage(s+1) DMA + protects buffer reuse
        buf ^= 1;
    }

    // epilogue: D col = px (lane&15), row = quad*4+r -> co
    #pragma unroll
    for (int mt = 0; mt < 2; ++mt) {
        const int co0 = wid * 32 + mt * 16 + quad * 4;
        float bv[4];
        #pragma unroll
        for (int rr = 0; rr < 4; ++rr) bv[rr] = bias[co0 + rr];
        #pragma unroll
        for (int nt = 0; nt < 7; ++nt) {
            int j = nt * 16 + m;
            #pragma unroll
            for (int rr = 0; rr < 4; ++rr) {
                out[(((size_t)n * COUT + co0 + rr) * H_DIM + h) * W_DIM + j] =
                    acc[mt][nt][rr] + bv[rr];
            }
        }
    }
}

// ---------------------------------------------------------------
extern "C" void kernel_launch(void* const* d_in, const int* in_sizes, int n_in,
                              void* d_out, int out_size, void* d_ws, size_t ws_size,
                              hipStream_t stream) {
    const float* x      = (const float*)d_in[0];
    const float* w      = (const float*)d_in[1];
    const float* bias   = (const float*)d_in[2];
    const float* shifts = (const float*)d_in[3];
    float* out = (float*)d_out;

    __hip_bfloat16* y  = (__hip_bfloat16*)d_ws;                       // 77,070,336 B
    __hip_bfloat16* wr = (__hip_bfloat16*)((char*)d_ws + 77070336);   //    442,368 B

    repack_w_kernel<<<dim3((9 * COUT * CMID + 255) / 256), 256, 0, stream>>>(w, wr);
    shift_pow_kernel<<<dim3(H_DIM, 2, NB), 256, 0, stream>>>(x, shifts, y);
    conv_kernel<<<dim3(H_DIM * NB), 256, 0, stream>>>(
        (const __bf16*)y, (const __bf16*)wr, bias, out);
}